// Round 11
// baseline (387.518 us; speedup 1.0000x reference)
//
#include <hip/hip_runtime.h>

// 2-layer LSTM (H=50, B=4096, T=512, D_in=1) + FC(50->1), fused MFMA, round 25
// (= round-24 resubmitted verbatim; r10's bench was an infra failure --
// "MI355X container failed twice" at acquisition, before compile/verify).
//
// = round-23 EXACTLY (unified K=128 operand: HS ring[2] with h1 slots 0-49,
// bias@50=1.0, x@51, h2 at 64-113; L1 lags 1 step; 25 update-calls incl. the
// merged mixed tile; per-SIMD issue {7,6,6,6}) with the wave count halved
// 8 -> 4 (256 thr, 1 wave/SIMD).
//
// Rationale: wave-count series 16w=341us (r16) -> 8w=318us (r23) is monotone.
// Busy/SIMD/step ~873cyc (VALUBusy 58.6% of 1490) matches the issue model;
// the ~615cyc bubble is NOT fillable by co-resident waves (their phases are
// barrier-correlated: both waves on a SIMD read/compute/wait in lockstep), so
// extra waves only add barrier skew + trans-pipe arbitration collisions.
// 4 waves keeps per-SIMD issue IDENTICAL (critical SIMD: 7 update-calls, 20
// MFMAs, now one wave with 7 independent ILP chains - r20 showed the compiler
// interleaves these), halves barrier width again, removes arbitration, and
// launch_bounds(256,1) frees the full VGPR budget.
// Partition: w0 L0{0-3}+L1{0-2} (7); w1 L0{4-6}+L1{3-5}+XW; w2 L0{7-9}+
// L1{6-8}; w3 L0{10,11}+L1{9-11}+MIXED. Arithmetic bit-identical to r23.
// B-frag layout (r2-r13-verified): k -> ks=k>>5, lane=((k>>3)&3)*16+n, j=k&7.

#define TT 512
#define HH 50
#define BT 16
#define NTHR 256   // 4 waves
#define L2E 1.44269504f

typedef _Float16 half8 __attribute__((ext_vector_type(8)));
typedef float floatx4 __attribute__((ext_vector_type(4)));

static __device__ __forceinline__ float fexp2(float x) { return __builtin_amdgcn_exp2f(x); }
static __device__ __forceinline__ float frcp(float x)  { return __builtin_amdgcn_rcpf(x); }

// PRE-SCALED cell update (identical to r20-r23): inputs are s_g*gate
// (s = -log2e, -log2e, -2log2e, -log2e for i,f,g,o).
// c' = R*[c*(1+Ei)(1+Eg) + (1-Eg)(1+Ef)], R = rcp((1+Ef)(1+Ei)(1+Eg));
// h = sig(o)*tanh(c'), c clamped (NaN guard).
static __device__ __forceinline__ float cell_update(float gi, float gf, float gg,
                                                    float go, float& c) {
    float Ei = fexp2(gi);
    float Eg = fexp2(gg);
    float Ef = fexp2(gf);
    float Eo = fexp2(go);
    float p1 = (1.0f + Ei) * (1.0f + Eg);
    float fe = 1.0f + Ef;
    float R  = frcp(fe * p1);
    c = R * (c * p1 + (1.0f - Eg) * fe);
    float cl = fminf(fmaxf(c, -18.0f), 18.0f);
    float Ec = fexp2(cl * (-2.0f * L2E));
    float Ro = frcp((1.0f + Eo) * (1.0f + Ec));
    return (1.0f - Ec) * Ro;
}

#define MFMA(a, b, c) __builtin_amdgcn_mfma_f32_16x16x32_f16((a), (b), (c), 0, 0, 0)

static __device__ __forceinline__ int widx_of(int unit, int m) {
    return ((unit >> 5) * 64 + ((unit >> 3) & 3) * 16 + m) * 8 + (unit & 7);
}

// One wave: NL0 pure-L0 tiles (l0base..), NL1 pure-L1 tiles (l1base..),
// optional mixed tile (L0 u48/49 on lane-quads 0-1, L1 u48/49 on quads 2-3).
// XW wave maintains x slot 51.
template<int NL0, int NL1, bool MX, bool XW>
static __device__ __forceinline__ void run(
    int l0base, int l1base, int ln, _Float16 (*HS)[2048], const float* xs,
    const float* __restrict__ W_ih0, const float* __restrict__ W_hh0,
    const float* __restrict__ b_ih0, const float* __restrict__ b_hh0,
    const float* __restrict__ W_ih1, const float* __restrict__ W_hh1,
    const float* __restrict__ b_ih1, const float* __restrict__ b_hh1)
{
    const int m = ln & 15, q = ln >> 4;
    const float GSC[4] = { -L2E, -L2E, -2.0f * L2E, -L2E };
    const int  gA = m & 3;
    const float sA = GSC[gA];

    // ---- A-fragments ----
    half8 a0[NL0 ? NL0 : 1][2];            // L0: virtual K 0-63 only
    float c0[NL0 ? NL0 : 1];
    int   w0i[NL0 ? NL0 : 1];
#pragma unroll
    for (int j = 0; j < NL0; ++j) {
        const int uA = 4 * (l0base + j) + (m >> 2);   // <= 47, always valid
        const int wrow = gA * HH + uA;
#pragma unroll
        for (int ks = 0; ks < 2; ++ks) {
            half8 h8;
#pragma unroll
            for (int jj = 0; jj < 8; ++jj) {
                int k = ks * 32 + q * 8 + jj;
                float w = 0.f;
                if (k < HH)       w = W_hh0[wrow * HH + k];
                else if (k == 50) w = b_ih0[wrow] + b_hh0[wrow];
                else if (k == 51) w = W_ih0[wrow];          // W_ih0 is [4H x 1]
                h8[jj] = (_Float16)(sA * w);
            }
            a0[j][ks] = h8;
        }
        w0i[j] = widx_of(4 * (l0base + j) + q, m);
        c0[j] = 0.f;
    }

    half8 a1[NL1 ? NL1 : 1][4];            // L1: virtual K=128
    float c1[NL1 ? NL1 : 1];
    int   w1i[NL1 ? NL1 : 1];
#pragma unroll
    for (int j = 0; j < NL1; ++j) {
        const int uA = 4 * (l1base + j) + (m >> 2);   // <= 47
        const int wrow = gA * HH + uA;
#pragma unroll
        for (int ks = 0; ks < 4; ++ks) {
            half8 h8;
#pragma unroll
            for (int jj = 0; jj < 8; ++jj) {
                int k = ks * 32 + q * 8 + jj;
                float w = 0.f;
                if (k < HH)                      w = W_ih1[wrow * HH + k];
                else if (k == 50)                w = b_ih1[wrow] + b_hh1[wrow];
                else if (k >= 64 && k < 64 + HH) w = W_hh1[wrow * HH + (k - 64)];
                h8[jj] = (_Float16)(sA * w);
            }
            a1[j][ks] = h8;
        }
        w1i[j] = 1024 + widx_of(4 * (l1base + j) + q, m);
        c1[j] = 0.f;
    }

    half8 amx[4];                          // mixed tile: rows sel<2: L0 u48+sel;
    float cmx = 0.f;                       //             sel>=2: L1 u46+sel
    int   wmxi = 0;
    if (MX) {
        const int sel  = m >> 2;
        const bool lo  = (sel < 2);
        const int unit = lo ? (48 + sel) : (46 + sel);
        const int wrow = gA * HH + unit;
#pragma unroll
        for (int ks = 0; ks < 4; ++ks) {
            half8 h8;
#pragma unroll
            for (int jj = 0; jj < 8; ++jj) {
                int k = ks * 32 + q * 8 + jj;
                float w = 0.f;
                if (lo) {
                    if (k < HH)       w = W_hh0[wrow * HH + k];
                    else if (k == 50) w = b_ih0[wrow] + b_hh0[wrow];
                    else if (k == 51) w = W_ih0[wrow];
                } else {
                    if (k < HH)                      w = W_ih1[wrow * HH + k];
                    else if (k == 50)                w = b_ih1[wrow] + b_hh1[wrow];
                    else if (k >= 64 && k < 64 + HH) w = W_hh1[wrow * HH + (k - 64)];
                }
                h8[jj] = (_Float16)(sA * w);
            }
            amx[ks] = h8;
        }
        const int cu = (q < 2) ? (48 + q) : (46 + q);  // C-side unit per quad
        wmxi = ((q < 2) ? 0 : 1024) + widx_of(cu, m);
    }

    // ---- step 0: h1(0) from x(0) only -> HS[0] (h2 region stays zero) ----
    {
        const float xv = xs[m];
#pragma unroll
        for (int j = 0; j < NL0; ++j) {
            const int uC = 4 * (l0base + j) + q;
            float g4[4];
#pragma unroll
            for (int g = 0; g < 4; ++g) {
                int rg = g * HH + uC;
                g4[g] = GSC[g] * ((b_ih0[rg] + b_hh0[rg]) + W_ih0[rg] * xv);
            }
            float h = cell_update(g4[0], g4[1], g4[2], g4[3], c0[j]);
            HS[0][w0i[j]] = (_Float16)h;
        }
        if (MX) {
            if (q < 2) {                    // L0 rows only; cmx untouched on q>=2
                const int uC = 48 + q;
                float g4[4];
#pragma unroll
                for (int g = 0; g < 4; ++g) {
                    int rg = g * HH + uC;
                    g4[g] = GSC[g] * ((b_ih0[rg] + b_hh0[rg]) + W_ih0[rg] * xv);
                }
                float h = cell_update(g4[0], g4[1], g4[2], g4[3], cmx);
                HS[0][wmxi] = (_Float16)h;
            }
        }
    }
    __syncthreads();

    const floatx4 ZERO = { 0.f, 0.f, 0.f, 0.f };

    // step s (1..512): read HS[(s-1)&1]; L0 tiles -> h1(s); L1 tiles -> h2(s-1);
    // all writes -> HS[s&1]. XW writes x(s+1) into the write buffer's slot 51.
#define STEP(P, S)                                                          \
    {                                                                       \
        const _Float16* Rb = HS[(P)];                                       \
        _Float16*       Wb = HS[(P) ^ 1];                                   \
        if (XW) {                                                           \
            if (ln < 16)                                                    \
                Wb[(96 + ln) * 8 + 3] = (_Float16)xs[((S) + 1) * BT + ln];  \
        }                                                                   \
        half8 b0 = *(const half8*)&Rb[(0   + ln) * 8];                      \
        half8 b1 = *(const half8*)&Rb[(64  + ln) * 8];                      \
        half8 b2, b3;                                                       \
        if (NL1 > 0 || MX) {                                                \
            b2 = *(const half8*)&Rb[(128 + ln) * 8];                        \
            b3 = *(const half8*)&Rb[(192 + ln) * 8];                        \
        }                                                                   \
        _Pragma("unroll")                                                   \
        for (int j = 0; j < NL0; ++j) {                                     \
            floatx4 a = MFMA(a0[j][0], b0, ZERO);                           \
            a = MFMA(a0[j][1], b1, a);                                      \
            float h = cell_update(a[0], a[1], a[2], a[3], c0[j]);           \
            Wb[w0i[j]] = (_Float16)h;                                       \
        }                                                                   \
        _Pragma("unroll")                                                   \
        for (int j = 0; j < NL1; ++j) {                                     \
            floatx4 a = MFMA(a1[j][0], b0, ZERO);                           \
            a = MFMA(a1[j][1], b1, a);                                      \
            a = MFMA(a1[j][2], b2, a);                                      \
            a = MFMA(a1[j][3], b3, a);                                      \
            float h = cell_update(a[0], a[1], a[2], a[3], c1[j]);           \
            Wb[w1i[j]] = (_Float16)h;                                       \
        }                                                                   \
        if (MX) {                                                           \
            floatx4 a = MFMA(amx[0], b0, ZERO);                             \
            a = MFMA(amx[1], b1, a);                                        \
            a = MFMA(amx[2], b2, a);                                        \
            a = MFMA(amx[3], b3, a);                                        \
            float h = cell_update(a[0], a[1], a[2], a[3], cmx);             \
            Wb[wmxi] = (_Float16)h;                                         \
        }                                                                   \
        __syncthreads();                                                    \
    }

    for (int k = 0; k < 256; ++k) {
        STEP(0, 2 * k + 1);
        STEP(1, 2 * k + 2);
    }
#undef STEP
}

__global__ __launch_bounds__(NTHR, 1) void lstm_mfma(
    const float* __restrict__ x,
    const float* __restrict__ W_ih0, const float* __restrict__ W_hh0,
    const float* __restrict__ b_ih0, const float* __restrict__ b_hh0,
    const float* __restrict__ W_ih1, const float* __restrict__ W_hh1,
    const float* __restrict__ b_ih1, const float* __restrict__ b_hh1,
    const float* __restrict__ W_fc,  const float* __restrict__ b_fc,
    float* __restrict__ out)
{
    __shared__ __align__(16) _Float16 HS[2][2048];   // [ring][h1(0-63)|h2(64-127) lines]
    __shared__ float xs[(TT + 2) * BT];              // +2 zero pad rows

    const int tid = threadIdx.x;
    const int ln  = tid & 63;
    const int wv  = tid >> 6;              // 0..3
    const int b0g = blockIdx.x * BT;

    // ---------------- one-time staging ----------------
    for (int i = tid; i < BT * TT; i += NTHR) {
        int b = i & 15, t = i >> 4;
        xs[t * BT + b] = x[(size_t)(b0g + b) * TT + t];
    }
    if (tid < 2 * BT) xs[TT * BT + tid] = 0.f;
    for (int i = tid; i < 2 * 2048; i += NTHR) ((_Float16*)HS)[i] = (_Float16)0.f;
    __syncthreads();
    if (tid < 16) {
        // bias slot k=50 (line 96+n, j=2) == 1.0 in both ring buffers;
        // x(1) -> slot k=51 of HS[0] (read at step 1)
        HS[0][(96 + tid) * 8 + 2] = (_Float16)1.0f;
        HS[1][(96 + tid) * 8 + 2] = (_Float16)1.0f;
        HS[0][(96 + tid) * 8 + 3] = (_Float16)xs[BT + tid];
    }
    // (visibility: covered by run's post-prologue __syncthreads; prologue
    // writes touch disjoint addresses)

    // 25 update-calls on 4 waves (1 wave/SIMD); per-SIMD counts {7,6,6,6}:
    //   w0: L0{0-3}  L1{0-2}        (7)
    //   w1: L0{4-6}  L1{3-5}  +XW   (6)
    //   w2: L0{7-9}  L1{6-8}        (6)
    //   w3: L0{10,11} L1{9-11} +MX  (6)
    switch (wv) {
    case 0: run<4, 3, false, false>(0,  0, ln, HS, xs, W_ih0, W_hh0, b_ih0, b_hh0, W_ih1, W_hh1, b_ih1, b_hh1); break;
    case 1: run<3, 3, false, true >(4,  3, ln, HS, xs, W_ih0, W_hh0, b_ih0, b_hh0, W_ih1, W_hh1, b_ih1, b_hh1); break;
    case 2: run<3, 3, false, false>(7,  6, ln, HS, xs, W_ih0, W_hh0, b_ih0, b_hh0, W_ih1, W_hh1, b_ih1, b_hh1); break;
    default: run<2, 3, true, false>(10, 9, ln, HS, xs, W_ih0, W_hh0, b_ih0, b_hh0, W_ih1, W_hh1, b_ih1, b_hh1); break;
    }

    // -------- FC epilogue: h2(511) written at step 512 -> HS[0] h2-region --------
    if (tid < BT) {
        float a = b_fc[0];
        for (int u = 0; u < HH; ++u) {
            int idx = 1024 + ((u >> 5) * 64 + ((u >> 3) & 3) * 16 + tid) * 8 + (u & 7);
            a = fmaf((float)HS[0][idx], W_fc[u], a);
        }
        out[b0g + tid] = a;
    }
}

extern "C" void kernel_launch(void* const* d_in, const int* in_sizes, int n_in,
                              void* d_out, int out_size, void* d_ws, size_t ws_size,
                              hipStream_t stream) {
    const float* x     = (const float*)d_in[0];
    const float* W_ih0 = (const float*)d_in[1];
    const float* W_hh0 = (const float*)d_in[2];
    const float* b_ih0 = (const float*)d_in[3];
    const float* b_hh0 = (const float*)d_in[4];
    const float* W_ih1 = (const float*)d_in[5];
    const float* W_hh1 = (const float*)d_in[6];
    const float* b_ih1 = (const float*)d_in[7];
    const float* b_hh1 = (const float*)d_in[8];
    const float* W_fc  = (const float*)d_in[9];
    const float* b_fc  = (const float*)d_in[10];
    float* out = (float*)d_out;

    dim3 grid(4096 / BT);   // 256 blocks = 1/CU
    dim3 block(NTHR);       // 4 waves
    lstm_mfma<<<grid, block, 0, stream>>>(x, W_ih0, W_hh0, b_ih0, b_hh0,
                                          W_ih1, W_hh1, b_ih1, b_hh1,
                                          W_fc, b_fc, out);
}

// Round 12
// 354.264 us; speedup vs baseline: 1.0939x; 1.0939x over previous
//
#include <hip/hip_runtime.h>

// 2-layer LSTM (H=50, B=4096, T=512, D_in=1) + FC(50->1), fused MFMA, round 26.
//
// = round-23 (champion, 318.5us: unified K=128 operand, HS ring[2], h1@0-49,
// bias@50=1.0, x@51, h2@64-113, L1 lags 1 step, 25 update-calls, 8 waves,
// 1 barrier/step) with a LAYER-PURE wave partition:
//   L0 waves w0-w3: {4,3,3,2} tiles, read ONLY b0,b1  (2 ds_read_b128)
//   L1 waves w4-w7: {3,3,3,3+MX} tiles, read b0..b3   (4 ds_read_b128)
// Post-barrier LDS reads 30 -> 24 (~-72cyc of LDS pipe serialization, which
// sits on the critical path: the last wave's data arrives after the whole
// burst) and every SIMD pairs one short-MFMA L0 wave with one long-MFMA L1
// wave -> heterogeneous pipe demand at 2 waves/SIMD. Per-SIMD update-call
// balance unchanged {7,6,6,6} (SIMD_i = L0{4,3,3,2}_i + L1{3,3,3,4}_i).
// Wave-count verdict (r25): 4w=356us (chain exposed), 8w=318us (optimum),
// 16w=341us (old structure) -> keep 8. Per-tile arithmetic identical to
// r23-r25 -> absmax bit-identical.
// B-frag layout (r2-r13-verified): k -> ks=k>>5, lane=((k>>3)&3)*16+n, j=k&7.

#define TT 512
#define HH 50
#define BT 16
#define NTHR 512   // 8 waves
#define L2E 1.44269504f

typedef _Float16 half8 __attribute__((ext_vector_type(8)));
typedef float floatx4 __attribute__((ext_vector_type(4)));

static __device__ __forceinline__ float fexp2(float x) { return __builtin_amdgcn_exp2f(x); }
static __device__ __forceinline__ float frcp(float x)  { return __builtin_amdgcn_rcpf(x); }

// PRE-SCALED cell update (identical to r20-r25): inputs are s_g*gate
// (s = -log2e, -log2e, -2log2e, -log2e for i,f,g,o).
// c' = R*[c*(1+Ei)(1+Eg) + (1-Eg)(1+Ef)], R = rcp((1+Ef)(1+Ei)(1+Eg));
// h = sig(o)*tanh(c'), c clamped (NaN guard).
static __device__ __forceinline__ float cell_update(float gi, float gf, float gg,
                                                    float go, float& c) {
    float Ei = fexp2(gi);
    float Eg = fexp2(gg);
    float Ef = fexp2(gf);
    float Eo = fexp2(go);
    float p1 = (1.0f + Ei) * (1.0f + Eg);
    float fe = 1.0f + Ef;
    float R  = frcp(fe * p1);
    c = R * (c * p1 + (1.0f - Eg) * fe);
    float cl = fminf(fmaxf(c, -18.0f), 18.0f);
    float Ec = fexp2(cl * (-2.0f * L2E));
    float Ro = frcp((1.0f + Eo) * (1.0f + Ec));
    return (1.0f - Ec) * Ro;
}

#define MFMA(a, b, c) __builtin_amdgcn_mfma_f32_16x16x32_f16((a), (b), (c), 0, 0, 0)

static __device__ __forceinline__ int widx_of(int unit, int m) {
    return ((unit >> 5) * 64 + ((unit >> 3) & 3) * 16 + m) * 8 + (unit & 7);
}

// One wave: NL0 pure-L0 tiles (l0base..), NL1 pure-L1 tiles (l1base..),
// optional mixed tile (L0 u48/49 on lane-quads 0-1, L1 u48/49 on quads 2-3).
// XW wave maintains x slot 51. PRIO: persistent setprio(1) (7-call SIMD pair).
template<int NL0, int NL1, bool MX, bool XW, bool PRIO>
static __device__ __forceinline__ void run(
    int l0base, int l1base, int ln, _Float16 (*HS)[2048], const float* xs,
    const float* __restrict__ W_ih0, const float* __restrict__ W_hh0,
    const float* __restrict__ b_ih0, const float* __restrict__ b_hh0,
    const float* __restrict__ W_ih1, const float* __restrict__ W_hh1,
    const float* __restrict__ b_ih1, const float* __restrict__ b_hh1)
{
    const int m = ln & 15, q = ln >> 4;
    const float GSC[4] = { -L2E, -L2E, -2.0f * L2E, -L2E };
    const int  gA = m & 3;
    const float sA = GSC[gA];

    // ---- A-fragments ----
    half8 a0[NL0 ? NL0 : 1][2];            // L0: virtual K 0-63 only
    float c0[NL0 ? NL0 : 1];
    int   w0i[NL0 ? NL0 : 1];
#pragma unroll
    for (int j = 0; j < NL0; ++j) {
        const int uA = 4 * (l0base + j) + (m >> 2);   // <= 47, always valid
        const int wrow = gA * HH + uA;
#pragma unroll
        for (int ks = 0; ks < 2; ++ks) {
            half8 h8;
#pragma unroll
            for (int jj = 0; jj < 8; ++jj) {
                int k = ks * 32 + q * 8 + jj;
                float w = 0.f;
                if (k < HH)       w = W_hh0[wrow * HH + k];
                else if (k == 50) w = b_ih0[wrow] + b_hh0[wrow];
                else if (k == 51) w = W_ih0[wrow];          // W_ih0 is [4H x 1]
                h8[jj] = (_Float16)(sA * w);
            }
            a0[j][ks] = h8;
        }
        w0i[j] = widx_of(4 * (l0base + j) + q, m);
        c0[j] = 0.f;
    }

    half8 a1[NL1 ? NL1 : 1][4];            // L1: virtual K=128
    float c1[NL1 ? NL1 : 1];
    int   w1i[NL1 ? NL1 : 1];
#pragma unroll
    for (int j = 0; j < NL1; ++j) {
        const int uA = 4 * (l1base + j) + (m >> 2);   // <= 47
        const int wrow = gA * HH + uA;
#pragma unroll
        for (int ks = 0; ks < 4; ++ks) {
            half8 h8;
#pragma unroll
            for (int jj = 0; jj < 8; ++jj) {
                int k = ks * 32 + q * 8 + jj;
                float w = 0.f;
                if (k < HH)                      w = W_ih1[wrow * HH + k];
                else if (k == 50)                w = b_ih1[wrow] + b_hh1[wrow];
                else if (k >= 64 && k < 64 + HH) w = W_hh1[wrow * HH + (k - 64)];
                h8[jj] = (_Float16)(sA * w);
            }
            a1[j][ks] = h8;
        }
        w1i[j] = 1024 + widx_of(4 * (l1base + j) + q, m);
        c1[j] = 0.f;
    }

    half8 amx[4];                          // mixed tile: rows sel<2: L0 u48+sel;
    float cmx = 0.f;                       //             sel>=2: L1 u46+sel
    int   wmxi = 0;
    if (MX) {
        const int sel  = m >> 2;
        const bool lo  = (sel < 2);
        const int unit = lo ? (48 + sel) : (46 + sel);
        const int wrow = gA * HH + unit;
#pragma unroll
        for (int ks = 0; ks < 4; ++ks) {
            half8 h8;
#pragma unroll
            for (int jj = 0; jj < 8; ++jj) {
                int k = ks * 32 + q * 8 + jj;
                float w = 0.f;
                if (lo) {
                    if (k < HH)       w = W_hh0[wrow * HH + k];
                    else if (k == 50) w = b_ih0[wrow] + b_hh0[wrow];
                    else if (k == 51) w = W_ih0[wrow];
                } else {
                    if (k < HH)                      w = W_ih1[wrow * HH + k];
                    else if (k == 50)                w = b_ih1[wrow] + b_hh1[wrow];
                    else if (k >= 64 && k < 64 + HH) w = W_hh1[wrow * HH + (k - 64)];
                }
                h8[jj] = (_Float16)(sA * w);
            }
            amx[ks] = h8;
        }
        const int cu = (q < 2) ? (48 + q) : (46 + q);  // C-side unit per quad
        wmxi = ((q < 2) ? 0 : 1024) + widx_of(cu, m);
    }

    if (PRIO) __builtin_amdgcn_s_setprio(1);

    // ---- step 0: h1(0) from x(0) only -> HS[0] (h2 region stays zero) ----
    {
        const float xv = xs[m];
#pragma unroll
        for (int j = 0; j < NL0; ++j) {
            const int uC = 4 * (l0base + j) + q;
            float g4[4];
#pragma unroll
            for (int g = 0; g < 4; ++g) {
                int rg = g * HH + uC;
                g4[g] = GSC[g] * ((b_ih0[rg] + b_hh0[rg]) + W_ih0[rg] * xv);
            }
            float h = cell_update(g4[0], g4[1], g4[2], g4[3], c0[j]);
            HS[0][w0i[j]] = (_Float16)h;
        }
        if (MX) {
            if (q < 2) {                    // L0 rows only; cmx untouched on q>=2
                const int uC = 48 + q;
                float g4[4];
#pragma unroll
                for (int g = 0; g < 4; ++g) {
                    int rg = g * HH + uC;
                    g4[g] = GSC[g] * ((b_ih0[rg] + b_hh0[rg]) + W_ih0[rg] * xv);
                }
                float h = cell_update(g4[0], g4[1], g4[2], g4[3], cmx);
                HS[0][wmxi] = (_Float16)h;
            }
        }
    }
    __syncthreads();

    const floatx4 ZERO = { 0.f, 0.f, 0.f, 0.f };

    // step s (1..512): read HS[(s-1)&1]; L0 tiles -> h1(s); L1 tiles -> h2(s-1);
    // all writes -> HS[s&1]. XW writes x(s+1) into the write buffer's slot 51.
#define STEP(P, S)                                                          \
    {                                                                       \
        const _Float16* Rb = HS[(P)];                                       \
        _Float16*       Wb = HS[(P) ^ 1];                                   \
        if (XW) {                                                           \
            if (ln < 16)                                                    \
                Wb[(96 + ln) * 8 + 3] = (_Float16)xs[((S) + 1) * BT + ln];  \
        }                                                                   \
        half8 b0 = *(const half8*)&Rb[(0   + ln) * 8];                      \
        half8 b1 = *(const half8*)&Rb[(64  + ln) * 8];                      \
        half8 b2, b3;                                                       \
        if (NL1 > 0 || MX) {                                                \
            b2 = *(const half8*)&Rb[(128 + ln) * 8];                        \
            b3 = *(const half8*)&Rb[(192 + ln) * 8];                        \
        }                                                                   \
        _Pragma("unroll")                                                   \
        for (int j = 0; j < NL0; ++j) {                                     \
            floatx4 a = MFMA(a0[j][0], b0, ZERO);                           \
            a = MFMA(a0[j][1], b1, a);                                      \
            float h = cell_update(a[0], a[1], a[2], a[3], c0[j]);           \
            Wb[w0i[j]] = (_Float16)h;                                       \
        }                                                                   \
        _Pragma("unroll")                                                   \
        for (int j = 0; j < NL1; ++j) {                                     \
            floatx4 a = MFMA(a1[j][0], b0, ZERO);                           \
            a = MFMA(a1[j][1], b1, a);                                      \
            a = MFMA(a1[j][2], b2, a);                                      \
            a = MFMA(a1[j][3], b3, a);                                      \
            float h = cell_update(a[0], a[1], a[2], a[3], c1[j]);           \
            Wb[w1i[j]] = (_Float16)h;                                       \
        }                                                                   \
        if (MX) {                                                           \
            floatx4 a = MFMA(amx[0], b0, ZERO);                             \
            a = MFMA(amx[1], b1, a);                                        \
            a = MFMA(amx[2], b2, a);                                        \
            a = MFMA(amx[3], b3, a);                                        \
            float h = cell_update(a[0], a[1], a[2], a[3], cmx);             \
            Wb[wmxi] = (_Float16)h;                                         \
        }                                                                   \
        __syncthreads();                                                    \
    }

    for (int k = 0; k < 256; ++k) {
        STEP(0, 2 * k + 1);
        STEP(1, 2 * k + 2);
    }
#undef STEP
}

__global__ __launch_bounds__(NTHR, 2) void lstm_mfma(
    const float* __restrict__ x,
    const float* __restrict__ W_ih0, const float* __restrict__ W_hh0,
    const float* __restrict__ b_ih0, const float* __restrict__ b_hh0,
    const float* __restrict__ W_ih1, const float* __restrict__ W_hh1,
    const float* __restrict__ b_ih1, const float* __restrict__ b_hh1,
    const float* __restrict__ W_fc,  const float* __restrict__ b_fc,
    float* __restrict__ out)
{
    __shared__ __align__(16) _Float16 HS[2][2048];   // [ring][h1(0-63)|h2(64-127) lines]
    __shared__ float xs[(TT + 2) * BT];              // +2 zero pad rows

    const int tid = threadIdx.x;
    const int ln  = tid & 63;
    const int wv  = tid >> 6;              // 0..7
    const int b0g = blockIdx.x * BT;

    // ---------------- one-time staging ----------------
    for (int i = tid; i < BT * TT; i += NTHR) {
        int b = i & 15, t = i >> 4;
        xs[t * BT + b] = x[(size_t)(b0g + b) * TT + t];
    }
    if (tid < 2 * BT) xs[TT * BT + tid] = 0.f;
    for (int i = tid; i < 2 * 2048; i += NTHR) ((_Float16*)HS)[i] = (_Float16)0.f;
    __syncthreads();
    if (tid < 16) {
        // bias slot k=50 (line 96+n, j=2) == 1.0 in both ring buffers;
        // x(1) -> slot k=51 of HS[0] (read at step 1)
        HS[0][(96 + tid) * 8 + 2] = (_Float16)1.0f;
        HS[1][(96 + tid) * 8 + 2] = (_Float16)1.0f;
        HS[0][(96 + tid) * 8 + 3] = (_Float16)xs[BT + tid];
    }
    // (visibility: covered by run's post-prologue __syncthreads; prologue
    // writes touch disjoint addresses)

    // LAYER-PURE partition, 25 update-calls on 8 waves; SIMD (wv&3) counts
    // {4+3, 3+3, 3+3, 2+4} = {7,6,6,6}:
    //   w0: L0{0-3}          (reads b0,b1)      w4: L1{0-2}
    //   w1: L0{4-6}          (reads b0,b1)      w5: L1{3-5}
    //   w2: L0{7-9}  +XW     (reads b0,b1)      w6: L1{6-8}
    //   w3: L0{10,11}        (reads b0,b1)      w7: L1{9-11} +MX
    switch (wv) {
    case 0: run<4, 0, false, false, true >(0,  0, ln, HS, xs, W_ih0, W_hh0, b_ih0, b_hh0, W_ih1, W_hh1, b_ih1, b_hh1); break;
    case 1: run<3, 0, false, false, false>(4,  0, ln, HS, xs, W_ih0, W_hh0, b_ih0, b_hh0, W_ih1, W_hh1, b_ih1, b_hh1); break;
    case 2: run<3, 0, false, true,  false>(7,  0, ln, HS, xs, W_ih0, W_hh0, b_ih0, b_hh0, W_ih1, W_hh1, b_ih1, b_hh1); break;
    case 3: run<2, 0, false, false, false>(10, 0, ln, HS, xs, W_ih0, W_hh0, b_ih0, b_hh0, W_ih1, W_hh1, b_ih1, b_hh1); break;
    case 4: run<0, 3, false, false, true >(0,  0, ln, HS, xs, W_ih0, W_hh0, b_ih0, b_hh0, W_ih1, W_hh1, b_ih1, b_hh1); break;
    case 5: run<0, 3, false, false, false>(0,  3, ln, HS, xs, W_ih0, W_hh0, b_ih0, b_hh0, W_ih1, W_hh1, b_ih1, b_hh1); break;
    case 6: run<0, 3, false, false, false>(0,  6, ln, HS, xs, W_ih0, W_hh0, b_ih0, b_hh0, W_ih1, W_hh1, b_ih1, b_hh1); break;
    default: run<0, 3, true,  false, false>(0, 9, ln, HS, xs, W_ih0, W_hh0, b_ih0, b_hh0, W_ih1, W_hh1, b_ih1, b_hh1); break;
    }

    // -------- FC epilogue: h2(511) written at step 512 -> HS[0] h2-region --------
    if (tid < BT) {
        float a = b_fc[0];
        for (int u = 0; u < HH; ++u) {
            int idx = 1024 + ((u >> 5) * 64 + ((u >> 3) & 3) * 16 + tid) * 8 + (u & 7);
            a = fmaf((float)HS[0][idx], W_fc[u], a);
        }
        out[b0g + tid] = a;
    }
}

extern "C" void kernel_launch(void* const* d_in, const int* in_sizes, int n_in,
                              void* d_out, int out_size, void* d_ws, size_t ws_size,
                              hipStream_t stream) {
    const float* x     = (const float*)d_in[0];
    const float* W_ih0 = (const float*)d_in[1];
    const float* W_hh0 = (const float*)d_in[2];
    const float* b_ih0 = (const float*)d_in[3];
    const float* b_hh0 = (const float*)d_in[4];
    const float* W_ih1 = (const float*)d_in[5];
    const float* W_hh1 = (const float*)d_in[6];
    const float* b_ih1 = (const float*)d_in[7];
    const float* b_hh1 = (const float*)d_in[8];
    const float* W_fc  = (const float*)d_in[9];
    const float* b_fc  = (const float*)d_in[10];
    float* out = (float*)d_out;

    dim3 grid(4096 / BT);   // 256 blocks = 1/CU
    dim3 block(NTHR);       // 8 waves
    lstm_mfma<<<grid, block, 0, stream>>>(x, W_ih0, W_hh0, b_ih0, b_hh0,
                                          W_ih1, W_hh1, b_ih1, b_hh1,
                                          W_fc, b_fc, out);
}

// Round 13
// 350.154 us; speedup vs baseline: 1.1067x; 1.0117x over previous
//
#include <hip/hip_runtime.h>

// 2-layer LSTM (H=50, B=4096, T=512, D_in=1) + FC(50->1), fused MFMA, round 27
// = ROUND-23 VERBATIM (the champion, 318.5us dispatch). r26's layer-pure
// partition regressed (324us): mixed L0+L1 waves win because heterogeneous
// chain lengths inside each wave keep MFMA and trans pipes co-fed across the
// interval; homogeneous waves re-cluster the trans phase.
//
// Structure: unified K=128 operand. HS ring[2] x 4KB: K-slots 0-49 h1,
// 50 bias(=1.0), 51 x(t), 64-113 h2. At step s every wave reads HS[(s-1)&1]:
// L0 tiles use b0,b1; L1 tiles use b0..b3 (h1 via W_ih1, h2 via W_hh1) ->
// L1 computes h2(s-1) lagged 1 step; FC reads h2(511) after step 512.
// Units 48/49 of both layers merge into one mixed tile -> 25 update-calls
// (minimum: 100 unit-quads / 4 rows per call), per-SIMD {7,6,6,6} (min-max
// = ceil(25/4) = 7). 8 waves / 1 barrier per step (r25: 4w=356, r16: 16w=341
// -> 8 is the measured optimum).
// Wall model (12-round consistent): ~1490 cyc/step = ~870 issue floor +
// ~620 barrier/serial-chain bubble; all fill mechanisms falsified.
// B-frag layout (r2-r13-verified): k -> ks=k>>5, lane=((k>>3)&3)*16+n, j=k&7.

#define TT 512
#define HH 50
#define BT 16
#define NTHR 512   // 8 waves
#define L2E 1.44269504f

typedef _Float16 half8 __attribute__((ext_vector_type(8)));
typedef float floatx4 __attribute__((ext_vector_type(4)));

static __device__ __forceinline__ float fexp2(float x) { return __builtin_amdgcn_exp2f(x); }
static __device__ __forceinline__ float frcp(float x)  { return __builtin_amdgcn_rcpf(x); }

// PRE-SCALED cell update: inputs are s_g*gate (s = -log2e, -log2e, -2log2e,
// -log2e for i,f,g,o). c' = R*[c*(1+Ei)(1+Eg) + (1-Eg)(1+Ef)],
// R = rcp((1+Ef)(1+Ei)(1+Eg)); h = sig(o)*tanh(c'), c clamped (NaN guard).
static __device__ __forceinline__ float cell_update(float gi, float gf, float gg,
                                                    float go, float& c) {
    float Ei = fexp2(gi);
    float Eg = fexp2(gg);
    float Ef = fexp2(gf);
    float Eo = fexp2(go);
    float p1 = (1.0f + Ei) * (1.0f + Eg);
    float fe = 1.0f + Ef;
    float R  = frcp(fe * p1);
    c = R * (c * p1 + (1.0f - Eg) * fe);
    float cl = fminf(fmaxf(c, -18.0f), 18.0f);
    float Ec = fexp2(cl * (-2.0f * L2E));
    float Ro = frcp((1.0f + Eo) * (1.0f + Ec));
    return (1.0f - Ec) * Ro;
}

#define MFMA(a, b, c) __builtin_amdgcn_mfma_f32_16x16x32_f16((a), (b), (c), 0, 0, 0)

static __device__ __forceinline__ int widx_of(int unit, int m) {
    return ((unit >> 5) * 64 + ((unit >> 3) & 3) * 16 + m) * 8 + (unit & 7);
}

// One wave: NL0 pure-L0 tiles (l0base..), NL1 pure-L1 tiles (l1base..),
// optional mixed tile (L0 u48/49 on lane-quads 0-1, L1 u48/49 on quads 2-3).
// XW wave maintains x slot 51. PRIO: persistent setprio(1) (7-call SIMD).
template<int NL0, int NL1, bool MX, bool XW, bool PRIO>
static __device__ __forceinline__ void run(
    int l0base, int l1base, int ln, _Float16 (*HS)[2048], const float* xs,
    const float* __restrict__ W_ih0, const float* __restrict__ W_hh0,
    const float* __restrict__ b_ih0, const float* __restrict__ b_hh0,
    const float* __restrict__ W_ih1, const float* __restrict__ W_hh1,
    const float* __restrict__ b_ih1, const float* __restrict__ b_hh1)
{
    const int m = ln & 15, q = ln >> 4;
    const float GSC[4] = { -L2E, -L2E, -2.0f * L2E, -L2E };
    const int  gA = m & 3;
    const float sA = GSC[gA];

    // ---- A-fragments ----
    half8 a0[NL0 ? NL0 : 1][2];            // L0: virtual K 0-63 only
    float c0[NL0 ? NL0 : 1];
    int   w0i[NL0 ? NL0 : 1];
#pragma unroll
    for (int j = 0; j < NL0; ++j) {
        const int uA = 4 * (l0base + j) + (m >> 2);   // <= 47, always valid
        const int wrow = gA * HH + uA;
#pragma unroll
        for (int ks = 0; ks < 2; ++ks) {
            half8 h8;
#pragma unroll
            for (int jj = 0; jj < 8; ++jj) {
                int k = ks * 32 + q * 8 + jj;
                float w = 0.f;
                if (k < HH)       w = W_hh0[wrow * HH + k];
                else if (k == 50) w = b_ih0[wrow] + b_hh0[wrow];
                else if (k == 51) w = W_ih0[wrow];          // W_ih0 is [4H x 1]
                h8[jj] = (_Float16)(sA * w);
            }
            a0[j][ks] = h8;
        }
        w0i[j] = widx_of(4 * (l0base + j) + q, m);
        c0[j] = 0.f;
    }

    half8 a1[NL1 ? NL1 : 1][4];            // L1: virtual K=128
    float c1[NL1 ? NL1 : 1];
    int   w1i[NL1 ? NL1 : 1];
#pragma unroll
    for (int j = 0; j < NL1; ++j) {
        const int uA = 4 * (l1base + j) + (m >> 2);   // <= 47
        const int wrow = gA * HH + uA;
#pragma unroll
        for (int ks = 0; ks < 4; ++ks) {
            half8 h8;
#pragma unroll
            for (int jj = 0; jj < 8; ++jj) {
                int k = ks * 32 + q * 8 + jj;
                float w = 0.f;
                if (k < HH)                      w = W_ih1[wrow * HH + k];
                else if (k == 50)                w = b_ih1[wrow] + b_hh1[wrow];
                else if (k >= 64 && k < 64 + HH) w = W_hh1[wrow * HH + (k - 64)];
                h8[jj] = (_Float16)(sA * w);
            }
            a1[j][ks] = h8;
        }
        w1i[j] = 1024 + widx_of(4 * (l1base + j) + q, m);
        c1[j] = 0.f;
    }

    half8 amx[4];                          // mixed tile: rows sel<2: L0 u48+sel;
    float cmx = 0.f;                       //             sel>=2: L1 u46+sel
    int   wmxi = 0;
    if (MX) {
        const int sel  = m >> 2;
        const bool lo  = (sel < 2);
        const int unit = lo ? (48 + sel) : (46 + sel);
        const int wrow = gA * HH + unit;
#pragma unroll
        for (int ks = 0; ks < 4; ++ks) {
            half8 h8;
#pragma unroll
            for (int jj = 0; jj < 8; ++jj) {
                int k = ks * 32 + q * 8 + jj;
                float w = 0.f;
                if (lo) {
                    if (k < HH)       w = W_hh0[wrow * HH + k];
                    else if (k == 50) w = b_ih0[wrow] + b_hh0[wrow];
                    else if (k == 51) w = W_ih0[wrow];
                } else {
                    if (k < HH)                      w = W_ih1[wrow * HH + k];
                    else if (k == 50)                w = b_ih1[wrow] + b_hh1[wrow];
                    else if (k >= 64 && k < 64 + HH) w = W_hh1[wrow * HH + (k - 64)];
                }
                h8[jj] = (_Float16)(sA * w);
            }
            amx[ks] = h8;
        }
        const int cu = (q < 2) ? (48 + q) : (46 + q);  // C-side unit per quad
        wmxi = ((q < 2) ? 0 : 1024) + widx_of(cu, m);
    }

    if (PRIO) __builtin_amdgcn_s_setprio(1);

    // ---- step 0: h1(0) from x(0) only -> HS[0] (h2 region stays zero) ----
    {
        const float xv = xs[m];
#pragma unroll
        for (int j = 0; j < NL0; ++j) {
            const int uC = 4 * (l0base + j) + q;
            float g4[4];
#pragma unroll
            for (int g = 0; g < 4; ++g) {
                int rg = g * HH + uC;
                g4[g] = GSC[g] * ((b_ih0[rg] + b_hh0[rg]) + W_ih0[rg] * xv);
            }
            float h = cell_update(g4[0], g4[1], g4[2], g4[3], c0[j]);
            HS[0][w0i[j]] = (_Float16)h;
        }
        if (MX) {
            if (q < 2) {                    // L0 rows only; cmx untouched on q>=2
                const int uC = 48 + q;
                float g4[4];
#pragma unroll
                for (int g = 0; g < 4; ++g) {
                    int rg = g * HH + uC;
                    g4[g] = GSC[g] * ((b_ih0[rg] + b_hh0[rg]) + W_ih0[rg] * xv);
                }
                float h = cell_update(g4[0], g4[1], g4[2], g4[3], cmx);
                HS[0][wmxi] = (_Float16)h;
            }
        }
    }
    __syncthreads();

    const floatx4 ZERO = { 0.f, 0.f, 0.f, 0.f };

    // step s (1..512): read HS[(s-1)&1]; L0 tiles -> h1(s); L1 tiles -> h2(s-1);
    // all writes -> HS[s&1]. XW writes x(s+1) into the write buffer's slot 51.
#define STEP(P, S)                                                          \
    {                                                                       \
        const _Float16* Rb = HS[(P)];                                       \
        _Float16*       Wb = HS[(P) ^ 1];                                   \
        if (XW) {                                                           \
            if (ln < 16)                                                    \
                Wb[(96 + ln) * 8 + 3] = (_Float16)xs[((S) + 1) * BT + ln];  \
        }                                                                   \
        half8 b0 = *(const half8*)&Rb[(0   + ln) * 8];                      \
        half8 b1 = *(const half8*)&Rb[(64  + ln) * 8];                      \
        half8 b2, b3;                                                       \
        if (NL1 > 0 || MX) {                                                \
            b2 = *(const half8*)&Rb[(128 + ln) * 8];                        \
            b3 = *(const half8*)&Rb[(192 + ln) * 8];                        \
        }                                                                   \
        _Pragma("unroll")                                                   \
        for (int j = 0; j < NL0; ++j) {                                     \
            floatx4 a = MFMA(a0[j][0], b0, ZERO);                           \
            a = MFMA(a0[j][1], b1, a);                                      \
            float h = cell_update(a[0], a[1], a[2], a[3], c0[j]);           \
            Wb[w0i[j]] = (_Float16)h;                                       \
        }                                                                   \
        _Pragma("unroll")                                                   \
        for (int j = 0; j < NL1; ++j) {                                     \
            floatx4 a = MFMA(a1[j][0], b0, ZERO);                           \
            a = MFMA(a1[j][1], b1, a);                                      \
            a = MFMA(a1[j][2], b2, a);                                      \
            a = MFMA(a1[j][3], b3, a);                                      \
            float h = cell_update(a[0], a[1], a[2], a[3], c1[j]);           \
            Wb[w1i[j]] = (_Float16)h;                                       \
        }                                                                   \
        if (MX) {                                                           \
            floatx4 a = MFMA(amx[0], b0, ZERO);                             \
            a = MFMA(amx[1], b1, a);                                        \
            a = MFMA(amx[2], b2, a);                                        \
            a = MFMA(amx[3], b3, a);                                        \
            float h = cell_update(a[0], a[1], a[2], a[3], cmx);             \
            Wb[wmxi] = (_Float16)h;                                         \
        }                                                                   \
        __syncthreads();                                                    \
    }

    for (int k = 0; k < 256; ++k) {
        STEP(0, 2 * k + 1);
        STEP(1, 2 * k + 2);
    }
#undef STEP
}

__global__ __launch_bounds__(NTHR, 2) void lstm_mfma(
    const float* __restrict__ x,
    const float* __restrict__ W_ih0, const float* __restrict__ W_hh0,
    const float* __restrict__ b_ih0, const float* __restrict__ b_hh0,
    const float* __restrict__ W_ih1, const float* __restrict__ W_hh1,
    const float* __restrict__ b_ih1, const float* __restrict__ b_hh1,
    const float* __restrict__ W_fc,  const float* __restrict__ b_fc,
    float* __restrict__ out)
{
    __shared__ __align__(16) _Float16 HS[2][2048];   // [ring][h1(0-63)|h2(64-127) lines]
    __shared__ float xs[(TT + 2) * BT];              // +2 zero pad rows

    const int tid = threadIdx.x;
    const int ln  = tid & 63;
    const int wv  = tid >> 6;              // 0..7
    const int b0g = blockIdx.x * BT;

    // ---------------- one-time staging ----------------
    for (int i = tid; i < BT * TT; i += NTHR) {
        int b = i & 15, t = i >> 4;
        xs[t * BT + b] = x[(size_t)(b0g + b) * TT + t];
    }
    if (tid < 2 * BT) xs[TT * BT + tid] = 0.f;
    for (int i = tid; i < 2 * 2048; i += NTHR) ((_Float16*)HS)[i] = (_Float16)0.f;
    __syncthreads();
    if (tid < 16) {
        // bias slot k=50 (line 96+n, j=2) == 1.0 in both ring buffers;
        // x(1) -> slot k=51 of HS[0] (read at step 1)
        HS[0][(96 + tid) * 8 + 2] = (_Float16)1.0f;
        HS[1][(96 + tid) * 8 + 2] = (_Float16)1.0f;
        HS[0][(96 + tid) * 8 + 3] = (_Float16)xs[BT + tid];
    }
    // (visibility: covered by run's post-prologue __syncthreads; prologue
    // writes touch disjoint addresses)

    // 25 update-calls on 8 waves; SIMD (wv&3) update counts {7,6,6,6}:
    //   w0: L0{0-3}          w4: L1{3-5}            -> SIMD0: 7 (PRIO)
    //   w1: L0{4,5} L1{0} XW w5: L0{10} L1{6,7}     -> SIMD1: 6
    //   w2: L0{6,7} L1{1}    w6: L0{11} L1{8,9}     -> SIMD2: 6
    //   w3: L0{8,9} L1{2}    w7: L1{10,11} + MIXED  -> SIMD3: 6
    switch (wv) {
    case 0: run<4, 0, false, false, true >(0,  0, ln, HS, xs, W_ih0, W_hh0, b_ih0, b_hh0, W_ih1, W_hh1, b_ih1, b_hh1); break;
    case 1: run<2, 1, false, true,  false>(4,  0, ln, HS, xs, W_ih0, W_hh0, b_ih0, b_hh0, W_ih1, W_hh1, b_ih1, b_hh1); break;
    case 2: run<2, 1, false, false, false>(6,  1, ln, HS, xs, W_ih0, W_hh0, b_ih0, b_hh0, W_ih1, W_hh1, b_ih1, b_hh1); break;
    case 3: run<2, 1, false, false, false>(8,  2, ln, HS, xs, W_ih0, W_hh0, b_ih0, b_hh0, W_ih1, W_hh1, b_ih1, b_hh1); break;
    case 4: run<0, 3, false, false, true >(0,  3, ln, HS, xs, W_ih0, W_hh0, b_ih0, b_hh0, W_ih1, W_hh1, b_ih1, b_hh1); break;
    case 5: run<1, 2, false, false, false>(10, 6, ln, HS, xs, W_ih0, W_hh0, b_ih0, b_hh0, W_ih1, W_hh1, b_ih1, b_hh1); break;
    case 6: run<1, 2, false, false, false>(11, 8, ln, HS, xs, W_ih0, W_hh0, b_ih0, b_hh0, W_ih1, W_hh1, b_ih1, b_hh1); break;
    default: run<0, 2, true, false, false>(0, 10, ln, HS, xs, W_ih0, W_hh0, b_ih0, b_hh0, W_ih1, W_hh1, b_ih1, b_hh1); break;
    }

    // -------- FC epilogue: h2(511) written at step 512 -> HS[0] h2-region --------
    if (tid < BT) {
        float a = b_fc[0];
        for (int u = 0; u < HH; ++u) {
            int idx = 1024 + ((u >> 5) * 64 + ((u >> 3) & 3) * 16 + tid) * 8 + (u & 7);
            a = fmaf((float)HS[0][idx], W_fc[u], a);
        }
        out[b0g + tid] = a;
    }
}

extern "C" void kernel_launch(void* const* d_in, const int* in_sizes, int n_in,
                              void* d_out, int out_size, void* d_ws, size_t ws_size,
                              hipStream_t stream) {
    const float* x     = (const float*)d_in[0];
    const float* W_ih0 = (const float*)d_in[1];
    const float* W_hh0 = (const float*)d_in[2];
    const float* b_ih0 = (const float*)d_in[3];
    const float* b_hh0 = (const float*)d_in[4];
    const float* W_ih1 = (const float*)d_in[5];
    const float* W_hh1 = (const float*)d_in[6];
    const float* b_ih1 = (const float*)d_in[7];
    const float* b_hh1 = (const float*)d_in[8];
    const float* W_fc  = (const float*)d_in[9];
    const float* b_fc  = (const float*)d_in[10];
    float* out = (float*)d_out;

    dim3 grid(4096 / BT);   // 256 blocks = 1/CU
    dim3 block(NTHR);       // 8 waves
    lstm_mfma<<<grid, block, 0, stream>>>(x, W_ih0, W_hh0, b_ih0, b_hh0,
                                          W_ih1, W_hh1, b_ih1, b_hh1,
                                          W_fc, b_fc, out);
}